// Round 6
// baseline (2361.794 us; speedup 1.0000x reference)
//
#include <hip/hip_runtime.h>
#include <math.h>
#include <float.h>

#define NB 8
#define NC 24
#define NA 96
#define NW 96
#define NF 32
#define NHID 128
#define AW (NA*NW)           // 9216
#define NBC (NB*NC)          // 192
#define NEL ((size_t)NBC*AW) // 1769472

// packed fp32: <2 x float> fma -> v_pk_fma_f32 on gfx90a+/gfx950
typedef float v2f __attribute__((ext_vector_type(2)));
#ifndef __has_builtin
#define __has_builtin(x) 0
#endif
#if __has_builtin(__builtin_elementwise_fma)
#define PKFMA(a,b,c) __builtin_elementwise_fma((a),(b),(c))
#else
#define PKFMA(a,b,c) ((a)*(b)+(c))   // HIP default fp-contract fuses this
#endif

// ---------------------------------------------------------------- stats
__global__ __launch_bounds__(256) void stats_kernel(
    const float* __restrict__ x, const int* __restrict__ rows_len,
    const int* __restrict__ cols_len, float* __restrict__ stats)
{
    int bc = blockIdx.x;
    int R = rows_len[bc], L = cols_len[bc];
    const float* xp = x + (size_t)bc * AW;
    int n = R * L;
    float sx = 0.f, sxx = 0.f;
    for (int i = threadIdx.x; i < n; i += 256) {
        int a = i / L, w = i - a * L;
        float v = xp[a * NW + w];
        sx += v;
        sxx = fmaf(v, v, sxx);
    }
    __shared__ float r1[256], r2[256];
    r1[threadIdx.x] = sx; r2[threadIdx.x] = sxx;
    __syncthreads();
    for (int s = 128; s > 0; s >>= 1) {
        if (threadIdx.x < s) {
            r1[threadIdx.x] += r1[threadIdx.x + s];
            r2[threadIdx.x] += r2[threadIdx.x + s];
        }
        __syncthreads();
    }
    if (threadIdx.x == 0) {
        float fn = (float)n;
        float mean = r1[0] / fn;
        float var = fmaxf((r2[0] - r1[0] * r1[0] / fn) / (fn - 1.f), 0.f);
        float sd = fmaxf(sqrtf(var), 1e-12f);
        stats[2 * bc] = mean;
        stats[2 * bc + 1] = 1.f / sd;
    }
}

// ---------------------------------------------------------------- prep: transpose first 24 rows of each stack's W1
__global__ __launch_bounds__(256) void prep_kernel(
    const float* __restrict__ tw1, float* __restrict__ w1t)
{
    int i = blockIdx.x * 256 + threadIdx.x;     // [s][j][t]
    if (i >= 4 * NHID * 24) return;
    int s = i / (NHID * 24), r = i % (NHID * 24);
    int j = r / 24, t = r % 24;
    w1t[i] = tw1[(size_t)s * 64 * NHID + t * NHID + j];
}

// ---------------------------------------------------------------- t0 MLP (1->128->32), packed-f accumulation
__global__ __launch_bounds__(256) void t0_kernel(
    const float* __restrict__ x, const int* __restrict__ rows_len,
    const int* __restrict__ cols_len, const float* __restrict__ stats,
    const float* __restrict__ w1, const float* __restrict__ b1,
    const float* __restrict__ w2, const float* __restrict__ b2,
    float* __restrict__ h)
{
    int tid = threadIdx.x;
    int bc = blockIdx.x / 18;
    int base = (blockIdx.x % 18) * 512;
    int R = rows_len[bc], L = cols_len[bc];
    float mean = stats[2 * bc], rstd = stats[2 * bc + 1];

    int eA = base + tid, eB = eA + 256;
    int aA = eA / NW, wA = eA % NW;
    int aB = eB / NW, wB = eB % NW;
    bool vA = (aA < R) && (wA < L);
    bool vB = (aB < R) && (wB < L);
    size_t gA = (size_t)bc * AW + eA;
    float xA = vA ? (x[gA] - mean) * rstd : 0.f;
    float xB = vB ? (x[gA + 256] - mean) * rstd : 0.f;

    v2f oA[16], oB[16];
    const v2f* b22 = (const v2f*)b2;
    #pragma unroll
    for (int i = 0; i < 16; i++) { v2f bb = b22[i]; oA[i] = bb; oB[i] = bb; }
    for (int j = 0; j < NHID; j++) {
        float hA = fmaxf(fmaf(xA, w1[j], b1[j]), 0.f);
        float hB = fmaxf(fmaf(xB, w1[j], b1[j]), 0.f);
        const v2f* wr = (const v2f*)&w2[j * NF];
        v2f hA2 = {hA, hA}, hB2 = {hB, hB};
        #pragma unroll
        for (int i = 0; i < 16; i++) {
            v2f q = wr[i];
            oA[i] = PKFMA(hA2, q, oA[i]);
            oB[i] = PKFMA(hB2, q, oB[i]);
        }
    }
    float mA = vA ? 1.f : 0.f, mB = vB ? 1.f : 0.f;
    float* hp = h + (size_t)bc * NF * AW;
    #pragma unroll
    for (int f = 0; f < NF; f++) {
        hp[(size_t)f * AW + eA] = oA[f >> 1][f & 1] * mA;
        hp[(size_t)f * AW + eB] = oB[f >> 1][f & 1] * mB;
    }
}

// ---------------------------------------------------------------- pools: one block per (bc, f) plane
// native HW sin (v_sin_f32 via __sinf): pool runs ~42M sins/dispatch, libm
// sinf is a multi-inst polynomial; HW sin error ~1e-7 rel, absmax headroom ok.
__global__ __launch_bounds__(256) void pool_kernel(
    const float* __restrict__ h, float* __restrict__ rowsum,
    float* __restrict__ colsum, float* __restrict__ matsum,
    float* __restrict__ cmax)
{
    __shared__ float sred[4];
    __shared__ float scol[4][96];
    int blk = blockIdx.x;            // bc*32 + f
    int bc = blk >> 5, f = blk & 31;
    const float* p = h + (size_t)blk * AW;
    int tid = threadIdx.x;
    int lane = tid & 63, wv = tid >> 6;

    // ---- max over plane (coalesced strided pass)
    float mx = -FLT_MAX;
    for (int i = tid; i < AW; i += 256) mx = fmaxf(mx, p[i]);
    #pragma unroll
    for (int off = 32; off >= 1; off >>= 1) mx = fmaxf(mx, __shfl_xor(mx, off, 64));
    if (lane == 0) sred[wv] = mx;
    __syncthreads();
    if (tid == 0)
        cmax[bc * NF + f] = fmaxf(fmaxf(sred[0], sred[1]), fmaxf(sred[2], sred[3]));

    int mode = f & 3, k = f >> 2;
    if (mode == 1) {
        // row sums of sin: wave per row (rows wv, wv+4, ...)
        for (int r = 0; r < 24; r++) {
            int a = wv + 4 * r;
            float v1 = p[a * NW + lane];
            float s = __sinf(v1);
            if (lane < 32) s += __sinf(p[a * NW + 64 + lane]);
            #pragma unroll
            for (int off = 32; off >= 1; off >>= 1) s += __shfl_xor(s, off, 64);
            if (lane == 0) rowsum[(bc * NA + a) * 8 + k] = s;
        }
    } else if (mode == 2) {
        // col sums of sin: lane l accumulates col l (and 64+l for l<32)
        float acc0 = 0.f, acc1 = 0.f;
        for (int r = 0; r < 24; r++) {
            int a = wv + 4 * r;
            acc0 += __sinf(p[a * NW + lane]);
            if (lane < 32) acc1 += __sinf(p[a * NW + 64 + lane]);
        }
        scol[wv][lane] = acc0;
        if (lane < 32) scol[wv][64 + lane] = acc1;
        __syncthreads();
        if (tid < 96)
            colsum[(bc * NW + tid) * 8 + k] =
                scol[0][tid] + scol[1][tid] + scol[2][tid] + scol[3][tid];
    } else if (mode == 3) {
        // matrix sum of sin
        float s = 0.f;
        for (int i = tid; i < AW; i += 256) s += __sinf(p[i]);
        #pragma unroll
        for (int off = 32; off >= 1; off >>= 1) s += __shfl_xor(s, off, 64);
        __syncthreads();
        if (lane == 0) sred[wv] = s;
        __syncthreads();
        if (tid == 0) matsum[bc * 8 + k] = sred[0] + sred[1] + sred[2] + sred[3];
    }
}

// ---------------------------------------------------------------- precompute per-(bc): rowc[j][a], colc[j][w]
__global__ __launch_bounds__(256) void precomp_kernel(
    const float* __restrict__ rowsum, const float* __restrict__ colsum,
    const float* __restrict__ matsum, const float* __restrict__ cmax,
    const float* __restrict__ w1, const float* __restrict__ b1,
    float* __restrict__ rowc, float* __restrict__ colc)
{
    __shared__ float sbm[NF];
    __shared__ float sconst[NHID];
    int tid = threadIdx.x;
    int bc = blockIdx.x, b = bc / NC;
    if (tid < NF) {
        float m = cmax[(b * NC) * NF + tid];
        for (int c = 1; c < NC; c++) m = fmaxf(m, cmax[(b * NC + c) * NF + tid]);
        sbm[tid] = m;
    }
    __syncthreads();
    if (tid < NHID) {
        float v = b1[tid];
        const float* mp = matsum + bc * 8;
        #pragma unroll
        for (int k = 0; k < 8; k++) v = fmaf(mp[k], w1[(24 + k) * NHID + tid], v);
        #pragma unroll
        for (int f = 0; f < NF; f++) v = fmaf(sbm[f], w1[(32 + f) * NHID + tid], v);
        sconst[tid] = v;
    }
    __syncthreads();
    for (int i = tid; i < NHID * NA; i += 256) {
        int j = i / NA, aa = i - j * NA;
        const float* rp = rowsum + (bc * NA + aa) * 8;
        float v = sconst[j];
        #pragma unroll
        for (int k = 0; k < 8; k++) v = fmaf(rp[k], w1[(8 + k) * NHID + j], v);
        rowc[(size_t)bc * (NHID * NA) + i] = v;
    }
    for (int i = tid; i < NHID * NW; i += 256) {
        int j = i / NW, ww = i - j * NW;
        const float* cp = colsum + (bc * NW + ww) * 8;
        float v = 0.f;
        #pragma unroll
        for (int k = 0; k < 8; k++) v = fmaf(cp[k], w1[(16 + k) * NHID + j], v);
        colc[(size_t)bc * (NHID * NW) + i] = v;
    }
}

// ---------------------------------------------------------------- stack MLP v7: explicit 2-half f-split
// r4 lesson: the allocator refuses >40 VGPR schedules and secretly splits the
// 16-packed-acc loop, rematting the hidden chain per chunk (instrs/wave ~8.1K
// vs ~3K source). v7 makes the split EXPLICIT and minimal: two sequential
// half-loops, each with 8 packed accs (16 VGPR live) -> fits the 40-VGPR
// schedule with no further splitting; hidden chain recomputed exactly once.
// Per-f accumulation order over j unchanged -> rounding-exact vs v6.
__global__ __launch_bounds__(512) void mlp_kernel(
    float* __restrict__ h, const float* __restrict__ rowc,
    const float* __restrict__ colc, const int* __restrict__ rows_len,
    const int* __restrict__ cols_len, const float* __restrict__ w1t,
    const float* __restrict__ w2, const float* __restrict__ b2)
{
    __shared__ float scol[NHID * NW];   // [j][w]  48 KB, conflict-free reads
    __shared__ float srow[NHID * 8];    // [j][da]  4 KB, broadcast reads
    int tid = threadIdx.x;
    int bc = blockIdx.x / 18;
    int base = (blockIdx.x % 18) * 512;
    int a0 = base / NW;                 // block spans rows a0..a0+5

    const float* cg = colc + (size_t)bc * (NHID * NW);
    for (int i = tid; i < NHID * NW; i += 512) scol[i] = cg[i];
    const float* rg = rowc + (size_t)bc * (NHID * NA);
    for (int i = tid; i < NHID * 8; i += 512) {
        int j = i >> 3, da = i & 7, a = a0 + da;
        srow[i] = (a < NA) ? rg[j * NA + a] : 0.f;
    }
    __syncthreads();

    int R = rows_len[bc], L = cols_len[bc];
    int e = base + tid;
    int a = e / NW, w = e % NW;
    int da = a - a0;
    float mk = (a < R && w < L) ? 1.f : 0.f;

    float* hp = h + (size_t)bc * NF * AW;
    float p[8];
    #pragma unroll
    for (int k = 0; k < 8; k++) p[k] = __sinf(hp[(size_t)(4 * k) * AW + e]);
    v2f p2[4];
    #pragma unroll
    for (int t = 0; t < 4; t++) p2[t] = (v2f){p[2 * t], p[2 * t + 1]};

    #pragma unroll 1
    for (int half = 0; half < 2; half++) {
        const v2f* b22 = (const v2f*)b2 + half * 8;
        v2f o[8];
        #pragma unroll
        for (int i = 0; i < 8; i++) o[i] = b22[i];

        for (int j = 0; j < NHID; j++) {
            const v2f* w1r = (const v2f*)(w1t + j * 24);  // uniform -> s_load
            v2f u = {srow[j * 8 + da], scol[j * NW + w]};
            #pragma unroll
            for (int t = 0; t < 4; t++) u = PKFMA(p2[t], w1r[t], u);
            float v = fmaxf(u.x + u.y, 0.f);
            const v2f* w2r = (const v2f*)(w2 + j * NF) + half * 8;  // uniform
            v2f vv = {v, v};
            #pragma unroll
            for (int i = 0; i < 8; i++) o[i] = PKFMA(vv, w2r[i], o[i]);
        }
        #pragma unroll
        for (int i = 0; i < 8; i++) {             // residual read-modify-write
            int f = half * 16 + 2 * i;
            float* addr0 = hp + (size_t)f * AW + e;
            float* addr1 = hp + (size_t)(f + 1) * AW + e;
            *addr0 = (*addr0 + o[i].x) * mk;
            *addr1 = (*addr1 + o[i].y) * mk;
        }
    }
}

// ---------------------------------------------------------------- RMS over (a,w)
__global__ __launch_bounds__(256) void rms_kernel(
    const float* __restrict__ h, const int* __restrict__ rows_len,
    const int* __restrict__ cols_len, float* __restrict__ rms)
{
    int bc = blockIdx.x;
    int f = threadIdx.x >> 3, g = threadIdx.x & 7;
    const float* p = h + ((size_t)bc * NF + f) * AW;
    float s = 0.f;
    for (int i = g; i < AW; i += 8) { float v = p[i]; s = fmaf(v, v, s); }
    __shared__ float red[NF][9];
    red[f][g] = s;
    __syncthreads();
    if (threadIdx.x < NF) {
        float t = 0.f;
        #pragma unroll
        for (int g2 = 0; g2 < 8; g2++) t += red[threadIdx.x][g2];
        float n = (float)(rows_len[bc] * cols_len[bc]);
        t = fmaxf(t, 1e-20f);
        rms[bc * NF + threadIdx.x] = sqrtf(t / fmaxf(n, 1e-12f));
    }
}

// ---------------------------------------------------------------- final mean-over-C + MLP + tanh
__global__ __launch_bounds__(64) void out_kernel(
    const float* __restrict__ rms, const float* __restrict__ w1,
    const float* __restrict__ b1, const float* __restrict__ w2,
    const float* __restrict__ b2, float* __restrict__ out)
{
    int b = threadIdx.x;
    if (b >= NB) return;
    float hm[NF];
    #pragma unroll
    for (int f = 0; f < NF; f++) {
        float s = 0.f;
        for (int c = 0; c < NC; c++) s += rms[(b * NC + c) * NF + f];
        hm[f] = s / (float)NC;
    }
    float o0 = b2[0], o1 = b2[1];
    for (int j = 0; j < NHID; j++) {
        float v = b1[j];
        #pragma unroll
        for (int f = 0; f < NF; f++) v = fmaf(hm[f], w1[f * NHID + j], v);
        v = fmaxf(v, 0.f);
        o0 = fmaf(v, w2[j * 2 + 0], o0);
        o1 = fmaf(v, w2[j * 2 + 1], o1);
    }
    out[b * 2 + 0] = 8.f * tanhf(o0);
    out[b * 2 + 1] = 8.f * tanhf(o1);
}

// ---------------------------------------------------------------- launcher
extern "C" void kernel_launch(void* const* d_in, const int* in_sizes, int n_in,
                              void* d_out, int out_size, void* d_ws, size_t ws_size,
                              hipStream_t stream)
{
    const float* x    = (const float*)d_in[0];
    const int* rl     = (const int*)d_in[1];
    const int* cl     = (const int*)d_in[2];
    const float* t0w1 = (const float*)d_in[3];
    const float* t0b1 = (const float*)d_in[4];
    const float* t0w2 = (const float*)d_in[5];
    const float* t0b2 = (const float*)d_in[6];
    const float* tw1  = (const float*)d_in[7];
    const float* tb1  = (const float*)d_in[8];
    const float* tw2  = (const float*)d_in[9];
    const float* tb2  = (const float*)d_in[10];
    const float* ow1  = (const float*)d_in[11];
    const float* ob1  = (const float*)d_in[12];
    const float* ow2  = (const float*)d_in[13];
    const float* ob2  = (const float*)d_in[14];
    float* out = (float*)d_out;

    float* ws    = (float*)d_ws;
    float* h     = ws;                               // NEL*NF  (planar [bc][f][a*96+w])
    float* stats = h + NEL * NF;                     // 2*NBC
    float* rowb  = stats + 2 * NBC;                  // NBC*NA*8
    float* colb  = rowb + (size_t)NBC * NA * 8;      // NBC*NW*8
    float* matb  = colb + (size_t)NBC * NW * 8;      // NBC*8
    float* cmxb  = matb + NBC * 8;                   // NBC*NF
    float* rmsb  = cmxb + NBC * NF;                  // NBC*NF
    float* w1tb  = rmsb + NBC * NF;                  // 4*NHID*24
    float* rowcb = w1tb + 4 * NHID * 24;             // NBC*NHID*NA
    float* colcb = rowcb + (size_t)NBC * NHID * NA;  // NBC*NHID*NW

    stats_kernel<<<NBC, 256, 0, stream>>>(x, rl, cl, stats);
    prep_kernel<<<(4 * NHID * 24 + 255) / 256, 256, 0, stream>>>(tw1, w1tb);
    t0_kernel<<<(int)(NEL / 512), 256, 0, stream>>>(x, rl, cl, stats,
                                                    t0w1, t0b1, t0w2, t0b2, h);
    for (int s = 0; s < 4; s++) {
        pool_kernel<<<NBC * NF, 256, 0, stream>>>(h, rowb, colb, matb, cmxb);
        precomp_kernel<<<NBC, 256, 0, stream>>>(rowb, colb, matb, cmxb,
            tw1 + (size_t)s * 64 * NHID, tb1 + s * NHID, rowcb, colcb);
        mlp_kernel<<<NBC * 18, 512, 0, stream>>>(h, rowcb, colcb, rl, cl,
            w1tb + (size_t)s * NHID * 24,
            tw2 + (size_t)s * NHID * NF, tb2 + s * NF);
    }
    rms_kernel<<<NBC, 256, 0, stream>>>(h, rl, cl, rmsb);
    out_kernel<<<1, 64, 0, stream>>>(rmsb, ow1, ob1, ow2, ob2, out);
}

// Round 7
// 1849.747 us; speedup vs baseline: 1.2768x; 1.2768x over previous
//
#include <hip/hip_runtime.h>
#include <math.h>
#include <float.h>

#define NB 8
#define NC 24
#define NA 96
#define NW 96
#define NF 32
#define NHID 128
#define AW (NA*NW)           // 9216
#define NBC (NB*NC)          // 192
#define NEL ((size_t)NBC*AW) // 1769472
#define HSTR 18              // hid LDS row stride in dwords (16 used + 2 pad)

// packed fp32: <2 x float> fma -> v_pk_fma_f32 on gfx90a+/gfx950
typedef float v2f __attribute__((ext_vector_type(2)));
typedef float f32x4 __attribute__((ext_vector_type(4)));
typedef short short8_t __attribute__((ext_vector_type(8)));
#ifndef __has_builtin
#define __has_builtin(x) 0
#endif
#if __has_builtin(__builtin_elementwise_fma)
#define PKFMA(a,b,c) __builtin_elementwise_fma((a),(b),(c))
#else
#define PKFMA(a,b,c) ((a)*(b)+(c))
#endif

union frag_u { unsigned int u[4]; short8_t s; };

__device__ __forceinline__ unsigned short bf16rne(float x) {
    unsigned int u = __float_as_uint(x);
    unsigned int r = u + 0x7fffu + ((u >> 16) & 1u);
    return (unsigned short)(r >> 16);
}

// ---------------------------------------------------------------- stats
__global__ __launch_bounds__(256) void stats_kernel(
    const float* __restrict__ x, const int* __restrict__ rows_len,
    const int* __restrict__ cols_len, float* __restrict__ stats)
{
    int bc = blockIdx.x;
    int R = rows_len[bc], L = cols_len[bc];
    const float* xp = x + (size_t)bc * AW;
    int n = R * L;
    float sx = 0.f, sxx = 0.f;
    for (int i = threadIdx.x; i < n; i += 256) {
        int a = i / L, w = i - a * L;
        float v = xp[a * NW + w];
        sx += v;
        sxx = fmaf(v, v, sxx);
    }
    __shared__ float r1[256], r2[256];
    r1[threadIdx.x] = sx; r2[threadIdx.x] = sxx;
    __syncthreads();
    for (int s = 128; s > 0; s >>= 1) {
        if (threadIdx.x < s) {
            r1[threadIdx.x] += r1[threadIdx.x + s];
            r2[threadIdx.x] += r2[threadIdx.x + s];
        }
        __syncthreads();
    }
    if (threadIdx.x == 0) {
        float fn = (float)n;
        float mean = r1[0] / fn;
        float var = fmaxf((r2[0] - r1[0] * r1[0] / fn) / (fn - 1.f), 0.f);
        float sd = fmaxf(sqrtf(var), 1e-12f);
        stats[2 * bc] = mean;
        stats[2 * bc + 1] = 1.f / sd;
    }
}

// ---------------------------------------------------------------- prep: transpose first 24 rows of each stack's W1
__global__ __launch_bounds__(256) void prep_kernel(
    const float* __restrict__ tw1, float* __restrict__ w1t)
{
    int i = blockIdx.x * 256 + threadIdx.x;     // [s][j][t]
    if (i >= 4 * NHID * 24) return;
    int s = i / (NHID * 24), r = i % (NHID * 24);
    int j = r / 24, t = r % 24;
    w1t[i] = tw1[(size_t)s * 64 * NHID + t * NHID + j];
}

// ---------------------------------------------------------------- prep2: split W2^T into bf16 hi/lo (per stack)
// tw2 layout [s][j=128][f=32] -> w2bf[s][hi=0/lo=1][f][j] ushort
__global__ __launch_bounds__(256) void prep2_kernel(
    const float* __restrict__ tw2, unsigned short* __restrict__ w2bf)
{
    int i = blockIdx.x * 256 + threadIdx.x;
    if (i >= 4 * NF * NHID) return;
    int s = i / (NF * NHID), r = i % (NF * NHID);
    int f = r / NHID, j = r % NHID;
    float v = tw2[((size_t)s * NHID + j) * NF + f];
    unsigned short hi = bf16rne(v);
    float hf = __uint_as_float(((unsigned int)hi) << 16);
    unsigned short lo = bf16rne(v - hf);
    size_t base = (size_t)s * (2 * NF * NHID) + (size_t)f * NHID + j;
    w2bf[base] = hi;
    w2bf[base + NF * NHID] = lo;
}

// ---------------------------------------------------------------- t0 MLP (1->128->32), packed-f accumulation
__global__ __launch_bounds__(256) void t0_kernel(
    const float* __restrict__ x, const int* __restrict__ rows_len,
    const int* __restrict__ cols_len, const float* __restrict__ stats,
    const float* __restrict__ w1, const float* __restrict__ b1,
    const float* __restrict__ w2, const float* __restrict__ b2,
    float* __restrict__ h)
{
    int tid = threadIdx.x;
    int bc = blockIdx.x / 18;
    int base = (blockIdx.x % 18) * 512;
    int R = rows_len[bc], L = cols_len[bc];
    float mean = stats[2 * bc], rstd = stats[2 * bc + 1];

    int eA = base + tid, eB = eA + 256;
    int aA = eA / NW, wA = eA % NW;
    int aB = eB / NW, wB = eB % NW;
    bool vA = (aA < R) && (wA < L);
    bool vB = (aB < R) && (wB < L);
    size_t gA = (size_t)bc * AW + eA;
    float xA = vA ? (x[gA] - mean) * rstd : 0.f;
    float xB = vB ? (x[gA + 256] - mean) * rstd : 0.f;

    v2f oA[16], oB[16];
    const v2f* b22 = (const v2f*)b2;
    #pragma unroll
    for (int i = 0; i < 16; i++) { v2f bb = b22[i]; oA[i] = bb; oB[i] = bb; }
    for (int j = 0; j < NHID; j++) {
        float hA = fmaxf(fmaf(xA, w1[j], b1[j]), 0.f);
        float hB = fmaxf(fmaf(xB, w1[j], b1[j]), 0.f);
        const v2f* wr = (const v2f*)&w2[j * NF];
        v2f hA2 = {hA, hA}, hB2 = {hB, hB};
        #pragma unroll
        for (int i = 0; i < 16; i++) {
            v2f q = wr[i];
            oA[i] = PKFMA(hA2, q, oA[i]);
            oB[i] = PKFMA(hB2, q, oB[i]);
        }
    }
    float mA = vA ? 1.f : 0.f, mB = vB ? 1.f : 0.f;
    float* hp = h + (size_t)bc * NF * AW;
    #pragma unroll
    for (int f = 0; f < NF; f++) {
        hp[(size_t)f * AW + eA] = oA[f >> 1][f & 1] * mA;
        hp[(size_t)f * AW + eB] = oB[f >> 1][f & 1] * mB;
    }
}

// ---------------------------------------------------------------- pools: one block per (bc, f) plane
__global__ __launch_bounds__(256) void pool_kernel(
    const float* __restrict__ h, float* __restrict__ rowsum,
    float* __restrict__ colsum, float* __restrict__ matsum,
    float* __restrict__ cmax)
{
    __shared__ float sred[4];
    __shared__ float scol[4][96];
    int blk = blockIdx.x;            // bc*32 + f
    int bc = blk >> 5, f = blk & 31;
    const float* p = h + (size_t)blk * AW;
    int tid = threadIdx.x;
    int lane = tid & 63, wv = tid >> 6;

    float mx = -FLT_MAX;
    for (int i = tid; i < AW; i += 256) mx = fmaxf(mx, p[i]);
    #pragma unroll
    for (int off = 32; off >= 1; off >>= 1) mx = fmaxf(mx, __shfl_xor(mx, off, 64));
    if (lane == 0) sred[wv] = mx;
    __syncthreads();
    if (tid == 0)
        cmax[bc * NF + f] = fmaxf(fmaxf(sred[0], sred[1]), fmaxf(sred[2], sred[3]));

    int mode = f & 3, k = f >> 2;
    if (mode == 1) {
        for (int r = 0; r < 24; r++) {
            int a = wv + 4 * r;
            float v1 = p[a * NW + lane];
            float s = __sinf(v1);
            if (lane < 32) s += __sinf(p[a * NW + 64 + lane]);
            #pragma unroll
            for (int off = 32; off >= 1; off >>= 1) s += __shfl_xor(s, off, 64);
            if (lane == 0) rowsum[(bc * NA + a) * 8 + k] = s;
        }
    } else if (mode == 2) {
        float acc0 = 0.f, acc1 = 0.f;
        for (int r = 0; r < 24; r++) {
            int a = wv + 4 * r;
            acc0 += __sinf(p[a * NW + lane]);
            if (lane < 32) acc1 += __sinf(p[a * NW + 64 + lane]);
        }
        scol[wv][lane] = acc0;
        if (lane < 32) scol[wv][64 + lane] = acc1;
        __syncthreads();
        if (tid < 96)
            colsum[(bc * NW + tid) * 8 + k] =
                scol[0][tid] + scol[1][tid] + scol[2][tid] + scol[3][tid];
    } else if (mode == 3) {
        float s = 0.f;
        for (int i = tid; i < AW; i += 256) s += __sinf(p[i]);
        #pragma unroll
        for (int off = 32; off >= 1; off >>= 1) s += __shfl_xor(s, off, 64);
        __syncthreads();
        if (lane == 0) sred[wv] = s;
        __syncthreads();
        if (tid == 0) matsum[bc * 8 + k] = sred[0] + sred[1] + sred[2] + sred[3];
    }
}

// ---------------------------------------------------------------- precompute per-(bc): rowc[j][a], colc[j][w]
__global__ __launch_bounds__(256) void precomp_kernel(
    const float* __restrict__ rowsum, const float* __restrict__ colsum,
    const float* __restrict__ matsum, const float* __restrict__ cmax,
    const float* __restrict__ w1, const float* __restrict__ b1,
    float* __restrict__ rowc, float* __restrict__ colc)
{
    __shared__ float sbm[NF];
    __shared__ float sconst[NHID];
    int tid = threadIdx.x;
    int bc = blockIdx.x, b = bc / NC;
    if (tid < NF) {
        float m = cmax[(b * NC) * NF + tid];
        for (int c = 1; c < NC; c++) m = fmaxf(m, cmax[(b * NC + c) * NF + tid]);
        sbm[tid] = m;
    }
    __syncthreads();
    if (tid < NHID) {
        float v = b1[tid];
        const float* mp = matsum + bc * 8;
        #pragma unroll
        for (int k = 0; k < 8; k++) v = fmaf(mp[k], w1[(24 + k) * NHID + tid], v);
        #pragma unroll
        for (int f = 0; f < NF; f++) v = fmaf(sbm[f], w1[(32 + f) * NHID + tid], v);
        sconst[tid] = v;
    }
    __syncthreads();
    for (int i = tid; i < NHID * NA; i += 256) {
        int j = i / NA, aa = i - j * NA;
        const float* rp = rowsum + (bc * NA + aa) * 8;
        float v = sconst[j];
        #pragma unroll
        for (int k = 0; k < 8; k++) v = fmaf(rp[k], w1[(8 + k) * NHID + j], v);
        rowc[(size_t)bc * (NHID * NA) + i] = v;
    }
    for (int i = tid; i < NHID * NW; i += 256) {
        int j = i / NW, ww = i - j * NW;
        const float* cp = colsum + (bc * NW + ww) * 8;
        float v = 0.f;
        #pragma unroll
        for (int k = 0; k < 8; k++) v = fmaf(cp[k], w1[(16 + k) * NHID + j], v);
        colc[(size_t)bc * (NHID * NW) + i] = v;
    }
}

// ---------------------------------------------------------------- stack MLP v8: layer-1 VALU + layer-2 MFMA
// Block = 256 thr (4 waves), owns 256 consecutive e of one bc; 4 K-windows of
// 32 j. Phase A (per window): thread computes hidden fp32 for its element
// (identical math/order to v6 layer-1), splits to bf16 hi/lo, writes LDS.
// Phase B: mfma_f32_16x16x32_bf16 with A = W2^T (pre-split bf16 hi/lo),
// B = hidden, C = fp32 acc (init b2); 3-term split AhBh+AlBh+AhBl ~ fp32.
// C layout (m89): col=lane&15 -> e, row=(lane>>4)*4+reg (+16*tile) -> f.
__global__ __launch_bounds__(256) void mlp_kernel(
    float* __restrict__ h, const float* __restrict__ rowc,
    const float* __restrict__ colc, const int* __restrict__ rows_len,
    const int* __restrict__ cols_len, const float* __restrict__ w1t,
    const unsigned short* __restrict__ w2bf, const float* __restrict__ b2)
{
    __shared__ float scol32[32 * 96];          // [jj][w]   12 KB
    __shared__ float srow32[32 * 4];           // [jj][da]  0.5 KB
    __shared__ unsigned int hid_hi[256 * HSTR];// [e][jp]   18 KB
    __shared__ unsigned int hid_lo[256 * HSTR];// 18 KB     (total 48.5 KB -> 3 blk/CU)

    int tid = threadIdx.x;
    int bc = blockIdx.x / 36;
    int base = (blockIdx.x % 36) * 256;
    int a0 = base / NW;
    int lane = tid & 63, wv = tid >> 6;
    int g = lane >> 4, c16 = lane & 15;

    // phase-A element for this thread
    int e = base + tid;
    int a = e / NW, wc = e - a * NW, da = a - a0;
    float* hp = h + (size_t)bc * NF * AW;

    // sin of the 8 e0 channels (planes 4k), hoisted across windows
    float p[8];
    #pragma unroll
    for (int k = 0; k < 8; k++) p[k] = __sinf(hp[(size_t)(4 * k) * AW + e]);
    v2f p2[4];
    #pragma unroll
    for (int t = 0; t < 4; t++) p2[t] = (v2f){p[2 * t], p[2 * t + 1]};

    const unsigned short* w2hi = w2bf;
    const unsigned short* w2lo = w2bf + NF * NHID;

    // accumulators: [e-tile][f-tile], init = b2 (reg r <-> f = 4g+r+16t)
    f32x4 acc[4][2];
    #pragma unroll
    for (int t = 0; t < 2; t++) {
        f32x4 bb = *(const f32x4*)(b2 + 16 * t + 4 * g);
        #pragma unroll
        for (int ti = 0; ti < 4; ti++) acc[ti][t] = bb;
    }

    const size_t rcb = (size_t)bc * (NHID * 96);

    for (int w = 0; w < 4; w++) {
        int jw = 32 * w;
        // ---- stage colc/rowc slice for this window
        for (int i = tid; i < 32 * 96; i += 256)
            scol32[i] = colc[rcb + (size_t)jw * 96 + i];
        if (tid < 128) {
            int jj = tid >> 2, dd = tid & 3;
            int aa = a0 + dd;
            srow32[tid] = (aa < NA) ? rowc[rcb + (size_t)(jw + jj) * 96 + aa] : 0.f;
        }
        // ---- A-fragments for this window (issued pre-barrier, used in phase B)
        frag_u Ah[2], Al[2];
        #pragma unroll
        for (int t = 0; t < 2; t++) {
            size_t off = (size_t)(c16 + 16 * t) * NHID + jw + 8 * g;  // 16B-aligned
            const unsigned int* ph = (const unsigned int*)(w2hi + off);
            const unsigned int* pl = (const unsigned int*)(w2lo + off);
            #pragma unroll
            for (int d = 0; d < 4; d++) { Ah[t].u[d] = ph[d]; Al[t].u[d] = pl[d]; }
        }
        __syncthreads();   // staging visible; hid free from previous window

        // ---- phase A: hidden fp32 -> bf16 hi/lo -> LDS
        for (int jp = 0; jp < 16; jp++) {
            int jl = 2 * jp;
            const v2f* w1r0 = (const v2f*)(w1t + (size_t)(jw + jl) * 24);
            const v2f* w1r1 = (const v2f*)(w1t + (size_t)(jw + jl + 1) * 24);
            v2f u0 = {srow32[jl * 4 + da], scol32[jl * 96 + wc]};
            v2f u1 = {srow32[jl * 4 + 4 + da], scol32[jl * 96 + 96 + wc]};
            #pragma unroll
            for (int t = 0; t < 4; t++) {
                u0 = PKFMA(p2[t], w1r0[t], u0);
                u1 = PKFMA(p2[t], w1r1[t], u1);
            }
            float v0 = fmaxf(u0.x + u0.y, 0.f);
            float v1 = fmaxf(u1.x + u1.y, 0.f);
            unsigned int hi, lo;
            asm("v_cvt_pk_bf16_f32 %0, %1, %2" : "=v"(hi) : "v"(v0), "v"(v1));
            float h0 = __uint_as_float(hi << 16);
            float h1 = __uint_as_float(hi & 0xffff0000u);
            float l0 = v0 - h0, l1 = v1 - h1;
            asm("v_cvt_pk_bf16_f32 %0, %1, %2" : "=v"(lo) : "v"(l0), "v"(l1));
            hid_hi[tid * HSTR + jp] = hi;
            hid_lo[tid * HSTR + jp] = lo;
        }
        __syncthreads();   // hidden visible

        // ---- phase B: MFMA over this K-window; wave wv owns e-tiles 4wv..4wv+3
        #pragma unroll
        for (int ti = 0; ti < 4; ti++) {
            int el = (wv * 4 + ti) * 16 + c16;
            const unsigned int* bh = &hid_hi[el * HSTR + 4 * g];
            const unsigned int* bl = &hid_lo[el * HSTR + 4 * g];
            frag_u Bh, Bl;
            #pragma unroll
            for (int d = 0; d < 4; d++) { Bh.u[d] = bh[d]; Bl.u[d] = bl[d]; }
            #pragma unroll
            for (int t = 0; t < 2; t++) {
                acc[ti][t] = __builtin_amdgcn_mfma_f32_16x16x32_bf16(Ah[t].s, Bh.s, acc[ti][t], 0, 0, 0);
                acc[ti][t] = __builtin_amdgcn_mfma_f32_16x16x32_bf16(Al[t].s, Bh.s, acc[ti][t], 0, 0, 0);
                acc[ti][t] = __builtin_amdgcn_mfma_f32_16x16x32_bf16(Ah[t].s, Bl.s, acc[ti][t], 0, 0, 0);
            }
        }
        __syncthreads();   // hid consumed; safe to overwrite next window
    }

    // ---- epilogue: residual RMW + mask; lane covers e = base+el, f = 4g+r+16t
    int R = rows_len[bc], L = cols_len[bc];
    #pragma unroll
    for (int ti = 0; ti < 4; ti++) {
        int el = (wv * 4 + ti) * 16 + c16;
        int ee = base + el;
        int aa = ee / NW, ww = ee - aa * NW;
        float mk = (aa < R && ww < L) ? 1.f : 0.f;
        #pragma unroll
        for (int t = 0; t < 2; t++) {
            #pragma unroll
            for (int r = 0; r < 4; r++) {
                int f = 4 * g + r + 16 * t;
                float* ad = hp + (size_t)f * AW + ee;
                *ad = (*ad + acc[ti][t][r]) * mk;
            }
        }
    }
}

// ---------------------------------------------------------------- RMS over (a,w)
__global__ __launch_bounds__(256) void rms_kernel(
    const float* __restrict__ h, const int* __restrict__ rows_len,
    const int* __restrict__ cols_len, float* __restrict__ rms)
{
    int bc = blockIdx.x;
    int f = threadIdx.x >> 3, g = threadIdx.x & 7;
    const float* p = h + ((size_t)bc * NF + f) * AW;
    float s = 0.f;
    for (int i = g; i < AW; i += 8) { float v = p[i]; s = fmaf(v, v, s); }
    __shared__ float red[NF][9];
    red[f][g] = s;
    __syncthreads();
    if (threadIdx.x < NF) {
        float t = 0.f;
        #pragma unroll
        for (int g2 = 0; g2 < 8; g2++) t += red[threadIdx.x][g2];
        float n = (float)(rows_len[bc] * cols_len[bc]);
        t = fmaxf(t, 1e-20f);
        rms[bc * NF + threadIdx.x] = sqrtf(t / fmaxf(n, 1e-12f));
    }
}

// ---------------------------------------------------------------- final mean-over-C + MLP + tanh
__global__ __launch_bounds__(64) void out_kernel(
    const float* __restrict__ rms, const float* __restrict__ w1,
    const float* __restrict__ b1, const float* __restrict__ w2,
    const float* __restrict__ b2, float* __restrict__ out)
{
    int b = threadIdx.x;
    if (b >= NB) return;
    float hm[NF];
    #pragma unroll
    for (int f = 0; f < NF; f++) {
        float s = 0.f;
        for (int c = 0; c < NC; c++) s += rms[(b * NC + c) * NF + f];
        hm[f] = s / (float)NC;
    }
    float o0 = b2[0], o1 = b2[1];
    for (int j = 0; j < NHID; j++) {
        float v = b1[j];
        #pragma unroll
        for (int f = 0; f < NF; f++) v = fmaf(hm[f], w1[f * NHID + j], v);
        v = fmaxf(v, 0.f);
        o0 = fmaf(v, w2[j * 2 + 0], o0);
        o1 = fmaf(v, w2[j * 2 + 1], o1);
    }
    out[b * 2 + 0] = 8.f * tanhf(o0);
    out[b * 2 + 1] = 8.f * tanhf(o1);
}

// ---------------------------------------------------------------- launcher
extern "C" void kernel_launch(void* const* d_in, const int* in_sizes, int n_in,
                              void* d_out, int out_size, void* d_ws, size_t ws_size,
                              hipStream_t stream)
{
    const float* x    = (const float*)d_in[0];
    const int* rl     = (const int*)d_in[1];
    const int* cl     = (const int*)d_in[2];
    const float* t0w1 = (const float*)d_in[3];
    const float* t0b1 = (const float*)d_in[4];
    const float* t0w2 = (const float*)d_in[5];
    const float* t0b2 = (const float*)d_in[6];
    const float* tw1  = (const float*)d_in[7];
    const float* tb1  = (const float*)d_in[8];
    const float* tw2  = (const float*)d_in[9];
    const float* tb2  = (const float*)d_in[10];
    const float* ow1  = (const float*)d_in[11];
    const float* ob1  = (const float*)d_in[12];
    const float* ow2  = (const float*)d_in[13];
    const float* ob2  = (const float*)d_in[14];
    float* out = (float*)d_out;

    float* ws    = (float*)d_ws;
    float* h     = ws;                               // NEL*NF  (planar [bc][f][a*96+w])
    float* stats = h + NEL * NF;                     // 2*NBC
    float* rowb  = stats + 2 * NBC;                  // NBC*NA*8
    float* colb  = rowb + (size_t)NBC * NA * 8;      // NBC*NW*8
    float* matb  = colb + (size_t)NBC * NW * 8;      // NBC*8
    float* cmxb  = matb + NBC * 8;                   // NBC*NF
    float* rmsb  = cmxb + NBC * NF;                  // NBC*NF
    float* w1tb  = rmsb + NBC * NF;                  // 4*NHID*24
    float* rowcb = w1tb + 4 * NHID * 24;             // NBC*NHID*NA
    float* colcb = rowcb + (size_t)NBC * NHID * NA;  // NBC*NHID*NW
    unsigned short* w2bfb = (unsigned short*)(colcb + (size_t)NBC * NHID * NW); // 4*2*NF*NHID ushort

    stats_kernel<<<NBC, 256, 0, stream>>>(x, rl, cl, stats);
    prep_kernel<<<(4 * NHID * 24 + 255) / 256, 256, 0, stream>>>(tw1, w1tb);
    prep2_kernel<<<(4 * NF * NHID + 255) / 256, 256, 0, stream>>>(tw2, w2bfb);
    t0_kernel<<<(int)(NEL / 512), 256, 0, stream>>>(x, rl, cl, stats,
                                                    t0w1, t0b1, t0w2, t0b2, h);
    for (int s = 0; s < 4; s++) {
        pool_kernel<<<NBC * NF, 256, 0, stream>>>(h, rowb, colb, matb, cmxb);
        precomp_kernel<<<NBC, 256, 0, stream>>>(rowb, colb, matb, cmxb,
            tw1 + (size_t)s * 64 * NHID, tb1 + s * NHID, rowcb, colcb);
        mlp_kernel<<<NBC * 36, 256, 0, stream>>>(h, rowcb, colcb, rl, cl,
            w1tb + (size_t)s * NHID * 24,
            w2bfb + (size_t)s * (2 * NF * NHID),
            tb2 + s * NF);
    }
    rms_kernel<<<NBC, 256, 0, stream>>>(h, rl, cl, rmsb);
    out_kernel<<<1, 64, 0, stream>>>(rmsb, ow1, ob1, ow2, ob2, out);
}

// Round 8
// 1511.488 us; speedup vs baseline: 1.5626x; 1.2238x over previous
//
#include <hip/hip_runtime.h>
#include <math.h>
#include <float.h>

#define NB 8
#define NC 24
#define NA 96
#define NW 96
#define NF 32
#define NHID 128
#define AW (NA*NW)           // 9216
#define NBC (NB*NC)          // 192
#define NEL ((size_t)NBC*AW) // 1769472
#define HSTR 17              // hid LDS row stride in dwords (16 used + 1 pad, ODD -> conflict-free)

// packed fp32: <2 x float> fma -> v_pk_fma_f32 on gfx90a+/gfx950
typedef float v2f __attribute__((ext_vector_type(2)));
typedef float f32x4 __attribute__((ext_vector_type(4)));
typedef short short8_t __attribute__((ext_vector_type(8)));
#ifndef __has_builtin
#define __has_builtin(x) 0
#endif
#if __has_builtin(__builtin_elementwise_fma)
#define PKFMA(a,b,c) __builtin_elementwise_fma((a),(b),(c))
#else
#define PKFMA(a,b,c) ((a)*(b)+(c))
#endif

union frag_u { unsigned int u[4]; short8_t s; };

__device__ __forceinline__ unsigned short bf16rne(float x) {
    unsigned int u = __float_as_uint(x);
    unsigned int r = u + 0x7fffu + ((u >> 16) & 1u);
    return (unsigned short)(r >> 16);
}

// ---------------------------------------------------------------- stats
__global__ __launch_bounds__(256) void stats_kernel(
    const float* __restrict__ x, const int* __restrict__ rows_len,
    const int* __restrict__ cols_len, float* __restrict__ stats)
{
    int bc = blockIdx.x;
    int R = rows_len[bc], L = cols_len[bc];
    const float* xp = x + (size_t)bc * AW;
    int n = R * L;
    float sx = 0.f, sxx = 0.f;
    for (int i = threadIdx.x; i < n; i += 256) {
        int a = i / L, w = i - a * L;
        float v = xp[a * NW + w];
        sx += v;
        sxx = fmaf(v, v, sxx);
    }
    __shared__ float r1[256], r2[256];
    r1[threadIdx.x] = sx; r2[threadIdx.x] = sxx;
    __syncthreads();
    for (int s = 128; s > 0; s >>= 1) {
        if (threadIdx.x < s) {
            r1[threadIdx.x] += r1[threadIdx.x + s];
            r2[threadIdx.x] += r2[threadIdx.x + s];
        }
        __syncthreads();
    }
    if (threadIdx.x == 0) {
        float fn = (float)n;
        float mean = r1[0] / fn;
        float var = fmaxf((r2[0] - r1[0] * r1[0] / fn) / (fn - 1.f), 0.f);
        float sd = fmaxf(sqrtf(var), 1e-12f);
        stats[2 * bc] = mean;
        stats[2 * bc + 1] = 1.f / sd;
    }
}

// ---------------------------------------------------------------- prep: transpose first 24 rows of each stack's W1
__global__ __launch_bounds__(256) void prep_kernel(
    const float* __restrict__ tw1, float* __restrict__ w1t)
{
    int i = blockIdx.x * 256 + threadIdx.x;     // [s][j][t]
    if (i >= 4 * NHID * 24) return;
    int s = i / (NHID * 24), r = i % (NHID * 24);
    int j = r / 24, t = r % 24;
    w1t[i] = tw1[(size_t)s * 64 * NHID + t * NHID + j];
}

// ---------------------------------------------------------------- prep2: split W2^T into bf16 hi/lo (per stack)
// tw2 layout [s][j=128][f=32] -> w2bf[s][hi=0/lo=1][f][j] ushort
__global__ __launch_bounds__(256) void prep2_kernel(
    const float* __restrict__ tw2, unsigned short* __restrict__ w2bf)
{
    int i = blockIdx.x * 256 + threadIdx.x;
    if (i >= 4 * NF * NHID) return;
    int s = i / (NF * NHID), r = i % (NF * NHID);
    int f = r / NHID, j = r % NHID;
    float v = tw2[((size_t)s * NHID + j) * NF + f];
    unsigned short hi = bf16rne(v);
    float hf = __uint_as_float(((unsigned int)hi) << 16);
    unsigned short lo = bf16rne(v - hf);
    size_t base = (size_t)s * (2 * NF * NHID) + (size_t)f * NHID + j;
    w2bf[base] = hi;
    w2bf[base + NF * NHID] = lo;
}

// ---------------------------------------------------------------- t0 MLP (1->128->32), packed-f accumulation
__global__ __launch_bounds__(256) void t0_kernel(
    const float* __restrict__ x, const int* __restrict__ rows_len,
    const int* __restrict__ cols_len, const float* __restrict__ stats,
    const float* __restrict__ w1, const float* __restrict__ b1,
    const float* __restrict__ w2, const float* __restrict__ b2,
    float* __restrict__ h)
{
    int tid = threadIdx.x;
    int bc = blockIdx.x / 18;
    int base = (blockIdx.x % 18) * 512;
    int R = rows_len[bc], L = cols_len[bc];
    float mean = stats[2 * bc], rstd = stats[2 * bc + 1];

    int eA = base + tid, eB = eA + 256;
    int aA = eA / NW, wA = eA % NW;
    int aB = eB / NW, wB = eB % NW;
    bool vA = (aA < R) && (wA < L);
    bool vB = (aB < R) && (wB < L);
    size_t gA = (size_t)bc * AW + eA;
    float xA = vA ? (x[gA] - mean) * rstd : 0.f;
    float xB = vB ? (x[gA + 256] - mean) * rstd : 0.f;

    v2f oA[16], oB[16];
    const v2f* b22 = (const v2f*)b2;
    #pragma unroll
    for (int i = 0; i < 16; i++) { v2f bb = b22[i]; oA[i] = bb; oB[i] = bb; }
    for (int j = 0; j < NHID; j++) {
        float hA = fmaxf(fmaf(xA, w1[j], b1[j]), 0.f);
        float hB = fmaxf(fmaf(xB, w1[j], b1[j]), 0.f);
        const v2f* wr = (const v2f*)&w2[j * NF];
        v2f hA2 = {hA, hA}, hB2 = {hB, hB};
        #pragma unroll
        for (int i = 0; i < 16; i++) {
            v2f q = wr[i];
            oA[i] = PKFMA(hA2, q, oA[i]);
            oB[i] = PKFMA(hB2, q, oB[i]);
        }
    }
    float mA = vA ? 1.f : 0.f, mB = vB ? 1.f : 0.f;
    float* hp = h + (size_t)bc * NF * AW;
    #pragma unroll
    for (int f = 0; f < NF; f++) {
        hp[(size_t)f * AW + eA] = oA[f >> 1][f & 1] * mA;
        hp[(size_t)f * AW + eB] = oB[f >> 1][f & 1] * mB;
    }
}

// ---------------------------------------------------------------- pools: one block per (bc, f) plane
__global__ __launch_bounds__(256) void pool_kernel(
    const float* __restrict__ h, float* __restrict__ rowsum,
    float* __restrict__ colsum, float* __restrict__ matsum,
    float* __restrict__ cmax)
{
    __shared__ float sred[4];
    __shared__ float scol[4][96];
    int blk = blockIdx.x;            // bc*32 + f
    int bc = blk >> 5, f = blk & 31;
    const float* p = h + (size_t)blk * AW;
    int tid = threadIdx.x;
    int lane = tid & 63, wv = tid >> 6;

    float mx = -FLT_MAX;
    for (int i = tid; i < AW; i += 256) mx = fmaxf(mx, p[i]);
    #pragma unroll
    for (int off = 32; off >= 1; off >>= 1) mx = fmaxf(mx, __shfl_xor(mx, off, 64));
    if (lane == 0) sred[wv] = mx;
    __syncthreads();
    if (tid == 0)
        cmax[bc * NF + f] = fmaxf(fmaxf(sred[0], sred[1]), fmaxf(sred[2], sred[3]));

    int mode = f & 3, k = f >> 2;
    if (mode == 1) {
        for (int r = 0; r < 24; r++) {
            int a = wv + 4 * r;
            float v1 = p[a * NW + lane];
            float s = __sinf(v1);
            if (lane < 32) s += __sinf(p[a * NW + 64 + lane]);
            #pragma unroll
            for (int off = 32; off >= 1; off >>= 1) s += __shfl_xor(s, off, 64);
            if (lane == 0) rowsum[(bc * NA + a) * 8 + k] = s;
        }
    } else if (mode == 2) {
        float acc0 = 0.f, acc1 = 0.f;
        for (int r = 0; r < 24; r++) {
            int a = wv + 4 * r;
            acc0 += __sinf(p[a * NW + lane]);
            if (lane < 32) acc1 += __sinf(p[a * NW + 64 + lane]);
        }
        scol[wv][lane] = acc0;
        if (lane < 32) scol[wv][64 + lane] = acc1;
        __syncthreads();
        if (tid < 96)
            colsum[(bc * NW + tid) * 8 + k] =
                scol[0][tid] + scol[1][tid] + scol[2][tid] + scol[3][tid];
    } else if (mode == 3) {
        float s = 0.f;
        for (int i = tid; i < AW; i += 256) s += __sinf(p[i]);
        #pragma unroll
        for (int off = 32; off >= 1; off >>= 1) s += __shfl_xor(s, off, 64);
        __syncthreads();
        if (lane == 0) sred[wv] = s;
        __syncthreads();
        if (tid == 0) matsum[bc * 8 + k] = sred[0] + sred[1] + sred[2] + sred[3];
    }
}

// ---------------------------------------------------------------- precompute per-(bc): rowc[j][a], colc[j][w]
__global__ __launch_bounds__(256) void precomp_kernel(
    const float* __restrict__ rowsum, const float* __restrict__ colsum,
    const float* __restrict__ matsum, const float* __restrict__ cmax,
    const float* __restrict__ w1, const float* __restrict__ b1,
    float* __restrict__ rowc, float* __restrict__ colc)
{
    __shared__ float sbm[NF];
    __shared__ float sconst[NHID];
    int tid = threadIdx.x;
    int bc = blockIdx.x, b = bc / NC;
    if (tid < NF) {
        float m = cmax[(b * NC) * NF + tid];
        for (int c = 1; c < NC; c++) m = fmaxf(m, cmax[(b * NC + c) * NF + tid]);
        sbm[tid] = m;
    }
    __syncthreads();
    if (tid < NHID) {
        float v = b1[tid];
        const float* mp = matsum + bc * 8;
        #pragma unroll
        for (int k = 0; k < 8; k++) v = fmaf(mp[k], w1[(24 + k) * NHID + tid], v);
        #pragma unroll
        for (int f = 0; f < NF; f++) v = fmaf(sbm[f], w1[(32 + f) * NHID + tid], v);
        sconst[tid] = v;
    }
    __syncthreads();
    for (int i = tid; i < NHID * NA; i += 256) {
        int j = i / NA, aa = i - j * NA;
        const float* rp = rowsum + (bc * NA + aa) * 8;
        float v = sconst[j];
        #pragma unroll
        for (int k = 0; k < 8; k++) v = fmaf(rp[k], w1[(8 + k) * NHID + j], v);
        rowc[(size_t)bc * (NHID * NA) + i] = v;
    }
    for (int i = tid; i < NHID * NW; i += 256) {
        int j = i / NW, ww = i - j * NW;
        const float* cp = colsum + (bc * NW + ww) * 8;
        float v = 0.f;
        #pragma unroll
        for (int k = 0; k < 8; k++) v = fmaf(cp[k], w1[(16 + k) * NHID + j], v);
        colc[(size_t)bc * (NHID * NW) + i] = v;
    }
}

// ---------------------------------------------------------------- stack MLP v9: MFMA layer-2, conflict-free LDS
// vs v8 (253us, 7.08M bank conflicts, 33% occ):
//  - HSTR 18->17 (odd stride): phase-A writes 2 lanes/bank (free), phase-B
//    b128 reads balanced across 32 banks -> conflicts ~0.
//  - scol/srow LDS staging dropped: colc read direct (coalesced, L2-resident,
//    shared by 36 blocks/bc); rowc broadcast reads. LDS 49.7->34.8 KB ->
//    4 blocks/CU = 16 waves (50% occ); barriers 3->2 per window.
// Numerics identical to v8 (same values, same order).
__global__ __launch_bounds__(256, 4) void mlp_kernel(
    float* __restrict__ h, const float* __restrict__ rowc,
    const float* __restrict__ colc, const int* __restrict__ rows_len,
    const int* __restrict__ cols_len, const float* __restrict__ w1t,
    const unsigned short* __restrict__ w2bf, const float* __restrict__ b2)
{
    __shared__ unsigned int hid_hi[256 * HSTR];  // [e][jp] 17.4 KB
    __shared__ unsigned int hid_lo[256 * HSTR];  // 17.4 KB  (total 34.8 KB)

    int tid = threadIdx.x;
    int bc = blockIdx.x / 36;
    int base = (blockIdx.x % 36) * 256;
    int lane = tid & 63, wv = tid >> 6;
    int g = lane >> 4, c16 = lane & 15;

    // phase-A element for this thread
    int e = base + tid;
    int a = e / NW, wc = e - a * NW;
    float* hp = h + (size_t)bc * NF * AW;

    // sin of the 8 e0 channels (planes 4k), hoisted across windows
    float p[8];
    #pragma unroll
    for (int k = 0; k < 8; k++) p[k] = __sinf(hp[(size_t)(4 * k) * AW + e]);
    v2f p2[4];
    #pragma unroll
    for (int t = 0; t < 4; t++) p2[t] = (v2f){p[2 * t], p[2 * t + 1]};

    const unsigned short* w2hi = w2bf;
    const unsigned short* w2lo = w2bf + NF * NHID;

    // accumulators: [e-tile][f-tile], init = b2 (reg r <-> f = 4g+r+16t)
    f32x4 acc[4][2];
    #pragma unroll
    for (int t = 0; t < 2; t++) {
        f32x4 bb = *(const f32x4*)(b2 + 16 * t + 4 * g);
        #pragma unroll
        for (int ti = 0; ti < 4; ti++) acc[ti][t] = bb;
    }

    const float* rcr = rowc + (size_t)bc * (NHID * NA);
    const float* rcc = colc + (size_t)bc * (NHID * NW);

    for (int w = 0; w < 4; w++) {
        int jw = 32 * w;
        // ---- A-fragments for this window (global, L2-broadcast; used in phase B)
        frag_u Ah[2], Al[2];
        #pragma unroll
        for (int t = 0; t < 2; t++) {
            size_t off = (size_t)(c16 + 16 * t) * NHID + jw + 8 * g;  // 16B-aligned
            const unsigned int* ph = (const unsigned int*)(w2hi + off);
            const unsigned int* pl = (const unsigned int*)(w2lo + off);
            #pragma unroll
            for (int d = 0; d < 4; d++) { Ah[t].u[d] = ph[d]; Al[t].u[d] = pl[d]; }
        }

        // ---- phase A: hidden fp32 -> bf16 hi/lo -> LDS (prev phase B done via
        //      trailing barrier of previous window)
        #pragma unroll 4
        for (int jp = 0; jp < 16; jp++) {
            int jl = 2 * jp;
            const v2f* w1r0 = (const v2f*)(w1t + (size_t)(jw + jl) * 24);
            const v2f* w1r1 = w1r0 + 12;
            v2f u0 = {rcr[(size_t)(jw + jl) * NA + a], rcc[(size_t)(jw + jl) * NW + wc]};
            v2f u1 = {rcr[(size_t)(jw + jl + 1) * NA + a], rcc[(size_t)(jw + jl + 1) * NW + wc]};
            #pragma unroll
            for (int t = 0; t < 4; t++) {
                u0 = PKFMA(p2[t], w1r0[t], u0);
                u1 = PKFMA(p2[t], w1r1[t], u1);
            }
            float v0 = fmaxf(u0.x + u0.y, 0.f);
            float v1 = fmaxf(u1.x + u1.y, 0.f);
            unsigned int hi, lo;
            asm("v_cvt_pk_bf16_f32 %0, %1, %2" : "=v"(hi) : "v"(v0), "v"(v1));
            float h0 = __uint_as_float(hi << 16);
            float h1 = __uint_as_float(hi & 0xffff0000u);
            float l0 = v0 - h0, l1 = v1 - h1;
            asm("v_cvt_pk_bf16_f32 %0, %1, %2" : "=v"(lo) : "v"(l0), "v"(l1));
            hid_hi[tid * HSTR + jp] = hi;
            hid_lo[tid * HSTR + jp] = lo;
        }
        __syncthreads();   // hidden visible

        // ---- phase B: MFMA over this K-window; wave wv owns e-tiles 4wv..4wv+3
        #pragma unroll
        for (int ti = 0; ti < 4; ti++) {
            int el = (wv * 4 + ti) * 16 + c16;
            const unsigned int* bh = &hid_hi[el * HSTR + 4 * g];
            const unsigned int* bl = &hid_lo[el * HSTR + 4 * g];
            frag_u Bh, Bl;
            #pragma unroll
            for (int d = 0; d < 4; d++) { Bh.u[d] = bh[d]; Bl.u[d] = bl[d]; }
            #pragma unroll
            for (int t = 0; t < 2; t++) {
                acc[ti][t] = __builtin_amdgcn_mfma_f32_16x16x32_bf16(Ah[t].s, Bh.s, acc[ti][t], 0, 0, 0);
                acc[ti][t] = __builtin_amdgcn_mfma_f32_16x16x32_bf16(Al[t].s, Bh.s, acc[ti][t], 0, 0, 0);
                acc[ti][t] = __builtin_amdgcn_mfma_f32_16x16x32_bf16(Ah[t].s, Bl.s, acc[ti][t], 0, 0, 0);
            }
        }
        __syncthreads();   // hid consumed; next window may overwrite
    }

    // ---- epilogue: residual RMW + mask; lane covers e = base+el, f = 4g+r+16t
    int R = rows_len[bc], L = cols_len[bc];
    #pragma unroll
    for (int ti = 0; ti < 4; ti++) {
        int el = (wv * 4 + ti) * 16 + c16;
        int ee = base + el;
        int aa = ee / NW, ww = ee - aa * NW;
        float mk = (aa < R && ww < L) ? 1.f : 0.f;
        #pragma unroll
        for (int t = 0; t < 2; t++) {
            #pragma unroll
            for (int r = 0; r < 4; r++) {
                int f = 4 * g + r + 16 * t;
                float* ad = hp + (size_t)f * AW + ee;
                *ad = (*ad + acc[ti][t][r]) * mk;
            }
        }
    }
}

// ---------------------------------------------------------------- RMS over (a,w)
__global__ __launch_bounds__(256) void rms_kernel(
    const float* __restrict__ h, const int* __restrict__ rows_len,
    const int* __restrict__ cols_len, float* __restrict__ rms)
{
    int bc = blockIdx.x;
    int f = threadIdx.x >> 3, g = threadIdx.x & 7;
    const float* p = h + ((size_t)bc * NF + f) * AW;
    float s = 0.f;
    for (int i = g; i < AW; i += 8) { float v = p[i]; s = fmaf(v, v, s); }
    __shared__ float red[NF][9];
    red[f][g] = s;
    __syncthreads();
    if (threadIdx.x < NF) {
        float t = 0.f;
        #pragma unroll
        for (int g2 = 0; g2 < 8; g2++) t += red[threadIdx.x][g2];
        float n = (float)(rows_len[bc] * cols_len[bc]);
        t = fmaxf(t, 1e-20f);
        rms[bc * NF + threadIdx.x] = sqrtf(t / fmaxf(n, 1e-12f));
    }
}

// ---------------------------------------------------------------- final mean-over-C + MLP + tanh
__global__ __launch_bounds__(64) void out_kernel(
    const float* __restrict__ rms, const float* __restrict__ w1,
    const float* __restrict__ b1, const float* __restrict__ w2,
    const float* __restrict__ b2, float* __restrict__ out)
{
    int b = threadIdx.x;
    if (b >= NB) return;
    float hm[NF];
    #pragma unroll
    for (int f = 0; f < NF; f++) {
        float s = 0.f;
        for (int c = 0; c < NC; c++) s += rms[(b * NC + c) * NF + f];
        hm[f] = s / (float)NC;
    }
    float o0 = b2[0], o1 = b2[1];
    for (int j = 0; j < NHID; j++) {
        float v = b1[j];
        #pragma unroll
        for (int f = 0; f < NF; f++) v = fmaf(hm[f], w1[f * NHID + j], v);
        v = fmaxf(v, 0.f);
        o0 = fmaf(v, w2[j * 2 + 0], o0);
        o1 = fmaf(v, w2[j * 2 + 1], o1);
    }
    out[b * 2 + 0] = 8.f * tanhf(o0);
    out[b * 2 + 1] = 8.f * tanhf(o1);
}

// ---------------------------------------------------------------- launcher
extern "C" void kernel_launch(void* const* d_in, const int* in_sizes, int n_in,
                              void* d_out, int out_size, void* d_ws, size_t ws_size,
                              hipStream_t stream)
{
    const float* x    = (const float*)d_in[0];
    const int* rl     = (const int*)d_in[1];
    const int* cl     = (const int*)d_in[2];
    const float* t0w1 = (const float*)d_in[3];
    const float* t0b1 = (const float*)d_in[4];
    const float* t0w2 = (const float*)d_in[5];
    const float* t0b2 = (const float*)d_in[6];
    const float* tw1  = (const float*)d_in[7];
    const float* tb1  = (const float*)d_in[8];
    const float* tw2  = (const float*)d_in[9];
    const float* tb2  = (const float*)d_in[10];
    const float* ow1  = (const float*)d_in[11];
    const float* ob1  = (const float*)d_in[12];
    const float* ow2  = (const float*)d_in[13];
    const float* ob2  = (const float*)d_in[14];
    float* out = (float*)d_out;

    float* ws    = (float*)d_ws;
    float* h     = ws;                               // NEL*NF  (planar [bc][f][a*96+w])
    float* stats = h + NEL * NF;                     // 2*NBC
    float* rowb  = stats + 2 * NBC;                  // NBC*NA*8
    float* colb  = rowb + (size_t)NBC * NA * 8;      // NBC*NW*8
    float* matb  = colb + (size_t)NBC * NW * 8;      // NBC*8
    float* cmxb  = matb + NBC * 8;                   // NBC*NF
    float* rmsb  = cmxb + NBC * NF;                  // NBC*NF
    float* w1tb  = rmsb + NBC * NF;                  // 4*NHID*24
    float* rowcb = w1tb + 4 * NHID * 24;             // NBC*NHID*NA
    float* colcb = rowcb + (size_t)NBC * NHID * NA;  // NBC*NHID*NW
    unsigned short* w2bfb = (unsigned short*)(colcb + (size_t)NBC * NHID * NW); // 4*2*NF*NHID ushort

    stats_kernel<<<NBC, 256, 0, stream>>>(x, rl, cl, stats);
    prep_kernel<<<(4 * NHID * 24 + 255) / 256, 256, 0, stream>>>(tw1, w1tb);
    prep2_kernel<<<(4 * NF * NHID + 255) / 256, 256, 0, stream>>>(tw2, w2bfb);
    t0_kernel<<<(int)(NEL / 512), 256, 0, stream>>>(x, rl, cl, stats,
                                                    t0w1, t0b1, t0w2, t0b2, h);
    for (int s = 0; s < 4; s++) {
        pool_kernel<<<NBC * NF, 256, 0, stream>>>(h, rowb, colb, matb, cmxb);
        precomp_kernel<<<NBC, 256, 0, stream>>>(rowb, colb, matb, cmxb,
            tw1 + (size_t)s * 64 * NHID, tb1 + s * NHID, rowcb, colcb);
        mlp_kernel<<<NBC * 36, 256, 0, stream>>>(h, rowcb, colcb, rl, cl,
            w1tb + (size_t)s * NHID * 24,
            w2bfb + (size_t)s * (2 * NF * NHID),
            tb2 + s * NF);
    }
    rms_kernel<<<NBC, 256, 0, stream>>>(h, rl, cl, rmsb);
    out_kernel<<<1, 64, 0, stream>>>(rmsb, ow1, ob1, ow2, ob2, out);
}

// Round 9
// 1503.445 us; speedup vs baseline: 1.5709x; 1.0053x over previous
//
#include <hip/hip_runtime.h>
#include <math.h>
#include <float.h>

#define NB 8
#define NC 24
#define NA 96
#define NW 96
#define NF 32
#define NHID 128
#define AW (NA*NW)           // 9216
#define NBC (NB*NC)          // 192
#define NEL ((size_t)NBC*AW) // 1769472
#define HSTR 17              // hid LDS row stride in dwords (16 used + 1 pad, ODD -> conflict-free)

// packed fp32: <2 x float> fma -> v_pk_fma_f32 on gfx90a+/gfx950
typedef float v2f __attribute__((ext_vector_type(2)));
typedef float f32x4 __attribute__((ext_vector_type(4)));
typedef short short8_t __attribute__((ext_vector_type(8)));
#ifndef __has_builtin
#define __has_builtin(x) 0
#endif
#if __has_builtin(__builtin_elementwise_fma)
#define PKFMA(a,b,c) __builtin_elementwise_fma((a),(b),(c))
#else
#define PKFMA(a,b,c) ((a)*(b)+(c))
#endif

union frag_u { unsigned int u[4]; short8_t s; };

__device__ __forceinline__ unsigned short bf16rne(float x) {
    unsigned int u = __float_as_uint(x);
    unsigned int r = u + 0x7fffu + ((u >> 16) & 1u);
    return (unsigned short)(r >> 16);
}

// ---------------------------------------------------------------- stats
__global__ __launch_bounds__(256) void stats_kernel(
    const float* __restrict__ x, const int* __restrict__ rows_len,
    const int* __restrict__ cols_len, float* __restrict__ stats)
{
    int bc = blockIdx.x;
    int R = rows_len[bc], L = cols_len[bc];
    const float* xp = x + (size_t)bc * AW;
    int n = R * L;
    float sx = 0.f, sxx = 0.f;
    for (int i = threadIdx.x; i < n; i += 256) {
        int a = i / L, w = i - a * L;
        float v = xp[a * NW + w];
        sx += v;
        sxx = fmaf(v, v, sxx);
    }
    __shared__ float r1[256], r2[256];
    r1[threadIdx.x] = sx; r2[threadIdx.x] = sxx;
    __syncthreads();
    for (int s = 128; s > 0; s >>= 1) {
        if (threadIdx.x < s) {
            r1[threadIdx.x] += r1[threadIdx.x + s];
            r2[threadIdx.x] += r2[threadIdx.x + s];
        }
        __syncthreads();
    }
    if (threadIdx.x == 0) {
        float fn = (float)n;
        float mean = r1[0] / fn;
        float var = fmaxf((r2[0] - r1[0] * r1[0] / fn) / (fn - 1.f), 0.f);
        float sd = fmaxf(sqrtf(var), 1e-12f);
        stats[2 * bc] = mean;
        stats[2 * bc + 1] = 1.f / sd;
    }
}

// ---------------------------------------------------------------- prep: transpose first 24 rows of each stack's W1
__global__ __launch_bounds__(256) void prep_kernel(
    const float* __restrict__ tw1, float* __restrict__ w1t)
{
    int i = blockIdx.x * 256 + threadIdx.x;     // [s][j][t]
    if (i >= 4 * NHID * 24) return;
    int s = i / (NHID * 24), r = i % (NHID * 24);
    int j = r / 24, t = r % 24;
    w1t[i] = tw1[(size_t)s * 64 * NHID + t * NHID + j];
}

// ---------------------------------------------------------------- prep2: split W2^T into bf16 hi/lo (per stack)
// tw2 layout [s][j=128][f=32] -> w2bf[s][hi=0/lo=1][f][j] ushort
__global__ __launch_bounds__(256) void prep2_kernel(
    const float* __restrict__ tw2, unsigned short* __restrict__ w2bf)
{
    int i = blockIdx.x * 256 + threadIdx.x;
    if (i >= 4 * NF * NHID) return;
    int s = i / (NF * NHID), r = i % (NF * NHID);
    int f = r / NHID, j = r % NHID;
    float v = tw2[((size_t)s * NHID + j) * NF + f];
    unsigned short hi = bf16rne(v);
    float hf = __uint_as_float(((unsigned int)hi) << 16);
    unsigned short lo = bf16rne(v - hf);
    size_t base = (size_t)s * (2 * NF * NHID) + (size_t)f * NHID + j;
    w2bf[base] = hi;
    w2bf[base + NF * NHID] = lo;
}

// ---------------------------------------------------------------- t0 MLP (1->128->32), packed-f accumulation
__global__ __launch_bounds__(256) void t0_kernel(
    const float* __restrict__ x, const int* __restrict__ rows_len,
    const int* __restrict__ cols_len, const float* __restrict__ stats,
    const float* __restrict__ w1, const float* __restrict__ b1,
    const float* __restrict__ w2, const float* __restrict__ b2,
    float* __restrict__ h)
{
    int tid = threadIdx.x;
    int bc = blockIdx.x / 18;
    int base = (blockIdx.x % 18) * 512;
    int R = rows_len[bc], L = cols_len[bc];
    float mean = stats[2 * bc], rstd = stats[2 * bc + 1];

    int eA = base + tid, eB = eA + 256;
    int aA = eA / NW, wA = eA % NW;
    int aB = eB / NW, wB = eB % NW;
    bool vA = (aA < R) && (wA < L);
    bool vB = (aB < R) && (wB < L);
    size_t gA = (size_t)bc * AW + eA;
    float xA = vA ? (x[gA] - mean) * rstd : 0.f;
    float xB = vB ? (x[gA + 256] - mean) * rstd : 0.f;

    v2f oA[16], oB[16];
    const v2f* b22 = (const v2f*)b2;
    #pragma unroll
    for (int i = 0; i < 16; i++) { v2f bb = b22[i]; oA[i] = bb; oB[i] = bb; }
    for (int j = 0; j < NHID; j++) {
        float hA = fmaxf(fmaf(xA, w1[j], b1[j]), 0.f);
        float hB = fmaxf(fmaf(xB, w1[j], b1[j]), 0.f);
        const v2f* wr = (const v2f*)&w2[j * NF];
        v2f hA2 = {hA, hA}, hB2 = {hB, hB};
        #pragma unroll
        for (int i = 0; i < 16; i++) {
            v2f q = wr[i];
            oA[i] = PKFMA(hA2, q, oA[i]);
            oB[i] = PKFMA(hB2, q, oB[i]);
        }
    }
    float mA = vA ? 1.f : 0.f, mB = vB ? 1.f : 0.f;
    float* hp = h + (size_t)bc * NF * AW;
    #pragma unroll
    for (int f = 0; f < NF; f++) {
        hp[(size_t)f * AW + eA] = oA[f >> 1][f & 1] * mA;
        hp[(size_t)f * AW + eB] = oB[f >> 1][f & 1] * mB;
    }
}

// ---------------------------------------------------------------- pools: one block per (bc, f) plane
__global__ __launch_bounds__(256) void pool_kernel(
    const float* __restrict__ h, float* __restrict__ rowsum,
    float* __restrict__ colsum, float* __restrict__ matsum,
    float* __restrict__ cmax)
{
    __shared__ float sred[4];
    __shared__ float scol[4][96];
    int blk = blockIdx.x;            // bc*32 + f
    int bc = blk >> 5, f = blk & 31;
    const float* p = h + (size_t)blk * AW;
    int tid = threadIdx.x;
    int lane = tid & 63, wv = tid >> 6;

    float mx = -FLT_MAX;
    for (int i = tid; i < AW; i += 256) mx = fmaxf(mx, p[i]);
    #pragma unroll
    for (int off = 32; off >= 1; off >>= 1) mx = fmaxf(mx, __shfl_xor(mx, off, 64));
    if (lane == 0) sred[wv] = mx;
    __syncthreads();
    if (tid == 0)
        cmax[bc * NF + f] = fmaxf(fmaxf(sred[0], sred[1]), fmaxf(sred[2], sred[3]));

    int mode = f & 3, k = f >> 2;
    if (mode == 1) {
        for (int r = 0; r < 24; r++) {
            int a = wv + 4 * r;
            float v1 = p[a * NW + lane];
            float s = __sinf(v1);
            if (lane < 32) s += __sinf(p[a * NW + 64 + lane]);
            #pragma unroll
            for (int off = 32; off >= 1; off >>= 1) s += __shfl_xor(s, off, 64);
            if (lane == 0) rowsum[(bc * NA + a) * 8 + k] = s;
        }
    } else if (mode == 2) {
        float acc0 = 0.f, acc1 = 0.f;
        for (int r = 0; r < 24; r++) {
            int a = wv + 4 * r;
            acc0 += __sinf(p[a * NW + lane]);
            if (lane < 32) acc1 += __sinf(p[a * NW + 64 + lane]);
        }
        scol[wv][lane] = acc0;
        if (lane < 32) scol[wv][64 + lane] = acc1;
        __syncthreads();
        if (tid < 96)
            colsum[(bc * NW + tid) * 8 + k] =
                scol[0][tid] + scol[1][tid] + scol[2][tid] + scol[3][tid];
    } else if (mode == 3) {
        float s = 0.f;
        for (int i = tid; i < AW; i += 256) s += __sinf(p[i]);
        #pragma unroll
        for (int off = 32; off >= 1; off >>= 1) s += __shfl_xor(s, off, 64);
        __syncthreads();
        if (lane == 0) sred[wv] = s;
        __syncthreads();
        if (tid == 0) matsum[bc * 8 + k] = sred[0] + sred[1] + sred[2] + sred[3];
    }
}

// ---------------------------------------------------------------- precompute per-(bc): rowc[j][a], colc[j][w]
__global__ __launch_bounds__(256) void precomp_kernel(
    const float* __restrict__ rowsum, const float* __restrict__ colsum,
    const float* __restrict__ matsum, const float* __restrict__ cmax,
    const float* __restrict__ w1, const float* __restrict__ b1,
    float* __restrict__ rowc, float* __restrict__ colc)
{
    __shared__ float sbm[NF];
    __shared__ float sconst[NHID];
    int tid = threadIdx.x;
    int bc = blockIdx.x, b = bc / NC;
    if (tid < NF) {
        float m = cmax[(b * NC) * NF + tid];
        for (int c = 1; c < NC; c++) m = fmaxf(m, cmax[(b * NC + c) * NF + tid]);
        sbm[tid] = m;
    }
    __syncthreads();
    if (tid < NHID) {
        float v = b1[tid];
        const float* mp = matsum + bc * 8;
        #pragma unroll
        for (int k = 0; k < 8; k++) v = fmaf(mp[k], w1[(24 + k) * NHID + tid], v);
        #pragma unroll
        for (int f = 0; f < NF; f++) v = fmaf(sbm[f], w1[(32 + f) * NHID + tid], v);
        sconst[tid] = v;
    }
    __syncthreads();
    for (int i = tid; i < NHID * NA; i += 256) {
        int j = i / NA, aa = i - j * NA;
        const float* rp = rowsum + (bc * NA + aa) * 8;
        float v = sconst[j];
        #pragma unroll
        for (int k = 0; k < 8; k++) v = fmaf(rp[k], w1[(8 + k) * NHID + j], v);
        rowc[(size_t)bc * (NHID * NA) + i] = v;
    }
    for (int i = tid; i < NHID * NW; i += 256) {
        int j = i / NW, ww = i - j * NW;
        const float* cp = colsum + (bc * NW + ww) * 8;
        float v = 0.f;
        #pragma unroll
        for (int k = 0; k < 8; k++) v = fmaf(cp[k], w1[(16 + k) * NHID + j], v);
        colc[(size_t)bc * (NHID * NW) + i] = v;
    }
}

// ---------------------------------------------------------------- stack MLP v10: MFMA layer-2 + fused RMS accum
// = v9 (best: conflict-free HSTR=17, direct global colc/rowc, 34.8 KB LDS)
// plus: when last!=0, the epilogue accumulates sum(h^2) per (bc,f) into sqsum
// (16-lane shfl reduce -> LDS atomic -> 1 global atomic per f per block) and
// SKIPS the h write-back (h is dead after the last stack) -> saves the entire
// 226 MB rms re-read AND 221 MB of h writes.
__global__ __launch_bounds__(256, 4) void mlp_kernel(
    float* __restrict__ h, const float* __restrict__ rowc,
    const float* __restrict__ colc, const int* __restrict__ rows_len,
    const int* __restrict__ cols_len, const float* __restrict__ w1t,
    const unsigned short* __restrict__ w2bf, const float* __restrict__ b2,
    float* __restrict__ sqsum, int last)
{
    __shared__ unsigned int hid_hi[256 * HSTR];  // [e][jp] 17.4 KB
    __shared__ unsigned int hid_lo[256 * HSTR];  // 17.4 KB  (total 34.8 KB)
    __shared__ float sq_lds[NF];

    int tid = threadIdx.x;
    int bc = blockIdx.x / 36;
    int base = (blockIdx.x % 36) * 256;
    int lane = tid & 63, wv = tid >> 6;
    int g = lane >> 4, c16 = lane & 15;

    if (tid < NF) sq_lds[tid] = 0.f;   // visible by first __syncthreads below

    // phase-A element for this thread
    int e = base + tid;
    int a = e / NW, wc = e - a * NW;
    float* hp = h + (size_t)bc * NF * AW;

    // sin of the 8 e0 channels (planes 4k), hoisted across windows
    float p[8];
    #pragma unroll
    for (int k = 0; k < 8; k++) p[k] = __sinf(hp[(size_t)(4 * k) * AW + e]);
    v2f p2[4];
    #pragma unroll
    for (int t = 0; t < 4; t++) p2[t] = (v2f){p[2 * t], p[2 * t + 1]};

    const unsigned short* w2hi = w2bf;
    const unsigned short* w2lo = w2bf + NF * NHID;

    // accumulators: [e-tile][f-tile], init = b2 (reg r <-> f = 4g+r+16t)
    f32x4 acc[4][2];
    #pragma unroll
    for (int t = 0; t < 2; t++) {
        f32x4 bb = *(const f32x4*)(b2 + 16 * t + 4 * g);
        #pragma unroll
        for (int ti = 0; ti < 4; ti++) acc[ti][t] = bb;
    }

    const float* rcr = rowc + (size_t)bc * (NHID * NA);
    const float* rcc = colc + (size_t)bc * (NHID * NW);

    for (int w = 0; w < 4; w++) {
        int jw = 32 * w;
        // ---- A-fragments for this window (global, L2-broadcast; used in phase B)
        frag_u Ah[2], Al[2];
        #pragma unroll
        for (int t = 0; t < 2; t++) {
            size_t off = (size_t)(c16 + 16 * t) * NHID + jw + 8 * g;  // 16B-aligned
            const unsigned int* ph = (const unsigned int*)(w2hi + off);
            const unsigned int* pl = (const unsigned int*)(w2lo + off);
            #pragma unroll
            for (int d = 0; d < 4; d++) { Ah[t].u[d] = ph[d]; Al[t].u[d] = pl[d]; }
        }

        // ---- phase A: hidden fp32 -> bf16 hi/lo -> LDS
        #pragma unroll 4
        for (int jp = 0; jp < 16; jp++) {
            int jl = 2 * jp;
            const v2f* w1r0 = (const v2f*)(w1t + (size_t)(jw + jl) * 24);
            const v2f* w1r1 = w1r0 + 12;
            v2f u0 = {rcr[(size_t)(jw + jl) * NA + a], rcc[(size_t)(jw + jl) * NW + wc]};
            v2f u1 = {rcr[(size_t)(jw + jl + 1) * NA + a], rcc[(size_t)(jw + jl + 1) * NW + wc]};
            #pragma unroll
            for (int t = 0; t < 4; t++) {
                u0 = PKFMA(p2[t], w1r0[t], u0);
                u1 = PKFMA(p2[t], w1r1[t], u1);
            }
            float v0 = fmaxf(u0.x + u0.y, 0.f);
            float v1 = fmaxf(u1.x + u1.y, 0.f);
            unsigned int hi, lo;
            asm("v_cvt_pk_bf16_f32 %0, %1, %2" : "=v"(hi) : "v"(v0), "v"(v1));
            float h0 = __uint_as_float(hi << 16);
            float h1 = __uint_as_float(hi & 0xffff0000u);
            float l0 = v0 - h0, l1 = v1 - h1;
            asm("v_cvt_pk_bf16_f32 %0, %1, %2" : "=v"(lo) : "v"(l0), "v"(l1));
            hid_hi[tid * HSTR + jp] = hi;
            hid_lo[tid * HSTR + jp] = lo;
        }
        __syncthreads();   // hidden visible

        // ---- phase B: MFMA over this K-window; wave wv owns e-tiles 4wv..4wv+3
        #pragma unroll
        for (int ti = 0; ti < 4; ti++) {
            int el = (wv * 4 + ti) * 16 + c16;
            const unsigned int* bh = &hid_hi[el * HSTR + 4 * g];
            const unsigned int* bl = &hid_lo[el * HSTR + 4 * g];
            frag_u Bh, Bl;
            #pragma unroll
            for (int d = 0; d < 4; d++) { Bh.u[d] = bh[d]; Bl.u[d] = bl[d]; }
            #pragma unroll
            for (int t = 0; t < 2; t++) {
                acc[ti][t] = __builtin_amdgcn_mfma_f32_16x16x32_bf16(Ah[t].s, Bh.s, acc[ti][t], 0, 0, 0);
                acc[ti][t] = __builtin_amdgcn_mfma_f32_16x16x32_bf16(Al[t].s, Bh.s, acc[ti][t], 0, 0, 0);
                acc[ti][t] = __builtin_amdgcn_mfma_f32_16x16x32_bf16(Ah[t].s, Bl.s, acc[ti][t], 0, 0, 0);
            }
        }
        __syncthreads();   // hid consumed; next window may overwrite
    }

    // ---- epilogue: residual RMW + mask; lane covers e = base+el, f = 4g+r+16t
    int R = rows_len[bc], L = cols_len[bc];
    float psum[2][4] = {{0.f, 0.f, 0.f, 0.f}, {0.f, 0.f, 0.f, 0.f}};
    #pragma unroll
    for (int ti = 0; ti < 4; ti++) {
        int el = (wv * 4 + ti) * 16 + c16;
        int ee = base + el;
        int aa = ee / NW, ww = ee - aa * NW;
        float mk = (aa < R && ww < L) ? 1.f : 0.f;
        #pragma unroll
        for (int t = 0; t < 2; t++) {
            #pragma unroll
            for (int r = 0; r < 4; r++) {
                int f = 4 * g + r + 16 * t;
                float* ad = hp + (size_t)f * AW + ee;
                float hv = (*ad + acc[ti][t][r]) * mk;
                if (!last) *ad = hv;
                else       psum[t][r] = fmaf(hv, hv, psum[t][r]);
            }
        }
    }
    if (last) {
        #pragma unroll
        for (int t = 0; t < 2; t++) {
            #pragma unroll
            for (int r = 0; r < 4; r++) {
                float v = psum[t][r];
                v += __shfl_xor(v, 1, 64);
                v += __shfl_xor(v, 2, 64);
                v += __shfl_xor(v, 4, 64);
                v += __shfl_xor(v, 8, 64);   // masks <16: stays within c16 group
                if (c16 == 0) atomicAdd(&sq_lds[4 * g + r + 16 * t], v);
            }
        }
        __syncthreads();
        if (tid < NF) atomicAdd(&sqsum[bc * NF + tid], sq_lds[tid]);
    }
}

// ---------------------------------------------------------------- final: rms from sqsum + mean-over-C + MLP + tanh
__global__ __launch_bounds__(64) void out_kernel(
    const float* __restrict__ sqsum, const int* __restrict__ rows_len,
    const int* __restrict__ cols_len, const float* __restrict__ w1,
    const float* __restrict__ b1, const float* __restrict__ w2,
    const float* __restrict__ b2, float* __restrict__ out)
{
    int b = threadIdx.x;
    if (b >= NB) return;
    float hm[NF];
    #pragma unroll
    for (int f = 0; f < NF; f++) hm[f] = 0.f;
    for (int c = 0; c < NC; c++) {
        int bc = b * NC + c;
        float n = (float)(rows_len[bc] * cols_len[bc]);
        float rdn = 1.f / fmaxf(n, 1e-12f);
        #pragma unroll
        for (int f = 0; f < NF; f++) {
            float q = fmaxf(sqsum[bc * NF + f], 1e-20f);
            hm[f] += sqrtf(q * rdn);
        }
    }
    #pragma unroll
    for (int f = 0; f < NF; f++) hm[f] *= (1.f / (float)NC);

    float o0 = b2[0], o1 = b2[1];
    for (int j = 0; j < NHID; j++) {
        float v = b1[j];
        #pragma unroll
        for (int f = 0; f < NF; f++) v = fmaf(hm[f], w1[f * NHID + j], v);
        v = fmaxf(v, 0.f);
        o0 = fmaf(v, w2[j * 2 + 0], o0);
        o1 = fmaf(v, w2[j * 2 + 1], o1);
    }
    out[b * 2 + 0] = 8.f * tanhf(o0);
    out[b * 2 + 1] = 8.f * tanhf(o1);
}

// ---------------------------------------------------------------- launcher
extern "C" void kernel_launch(void* const* d_in, const int* in_sizes, int n_in,
                              void* d_out, int out_size, void* d_ws, size_t ws_size,
                              hipStream_t stream)
{
    const float* x    = (const float*)d_in[0];
    const int* rl     = (const int*)d_in[1];
    const int* cl     = (const int*)d_in[2];
    const float* t0w1 = (const float*)d_in[3];
    const float* t0b1 = (const float*)d_in[4];
    const float* t0w2 = (const float*)d_in[5];
    const float* t0b2 = (const float*)d_in[6];
    const float* tw1  = (const float*)d_in[7];
    const float* tb1  = (const float*)d_in[8];
    const float* tw2  = (const float*)d_in[9];
    const float* tb2  = (const float*)d_in[10];
    const float* ow1  = (const float*)d_in[11];
    const float* ob1  = (const float*)d_in[12];
    const float* ow2  = (const float*)d_in[13];
    const float* ob2  = (const float*)d_in[14];
    float* out = (float*)d_out;

    float* ws    = (float*)d_ws;
    float* h     = ws;                               // NEL*NF  (planar [bc][f][a*96+w])
    float* stats = h + NEL * NF;                     // 2*NBC
    float* rowb  = stats + 2 * NBC;                  // NBC*NA*8
    float* colb  = rowb + (size_t)NBC * NA * 8;      // NBC*NW*8
    float* matb  = colb + (size_t)NBC * NW * 8;      // NBC*8
    float* cmxb  = matb + NBC * 8;                   // NBC*NF
    float* sqb   = cmxb + NBC * NF;                  // NBC*NF (sum of h^2)
    float* w1tb  = sqb + NBC * NF;                   // 4*NHID*24
    float* rowcb = w1tb + 4 * NHID * 24;             // NBC*NHID*NA
    float* colcb = rowcb + (size_t)NBC * NHID * NA;  // NBC*NHID*NW
    unsigned short* w2bfb = (unsigned short*)(colcb + (size_t)NBC * NHID * NW); // 4*2*NF*NHID ushort

    hipMemsetAsync(sqb, 0, NBC * NF * sizeof(float), stream);
    stats_kernel<<<NBC, 256, 0, stream>>>(x, rl, cl, stats);
    prep_kernel<<<(4 * NHID * 24 + 255) / 256, 256, 0, stream>>>(tw1, w1tb);
    prep2_kernel<<<(4 * NF * NHID + 255) / 256, 256, 0, stream>>>(tw2, w2bfb);
    t0_kernel<<<(int)(NEL / 512), 256, 0, stream>>>(x, rl, cl, stats,
                                                    t0w1, t0b1, t0w2, t0b2, h);
    for (int s = 0; s < 4; s++) {
        pool_kernel<<<NBC * NF, 256, 0, stream>>>(h, rowb, colb, matb, cmxb);
        precomp_kernel<<<NBC, 256, 0, stream>>>(rowb, colb, matb, cmxb,
            tw1 + (size_t)s * 64 * NHID, tb1 + s * NHID, rowcb, colcb);
        mlp_kernel<<<NBC * 36, 256, 0, stream>>>(h, rowcb, colcb, rl, cl,
            w1tb + (size_t)s * NHID * 24,
            w2bfb + (size_t)s * (2 * NF * NHID),
            tb2 + s * NF, sqb, (s == 3) ? 1 : 0);
    }
    out_kernel<<<1, 64, 0, stream>>>(sqb, rl, cl, ow1, ob1, ow2, ob2, out);
}